// Round 10
// baseline (679.258 us; speedup 1.0000x reference)
//
#include <hip/hip_runtime.h>
#include <hip/hip_cooperative_groups.h>

namespace cg = cooperative_groups;

#define B_SZ 1024
#define H_SZ 2048
#define E_SZ 1024
#define GRID 256
#define BLK  512
#define NTHR (GRID * BLK)   // 131072

typedef float  f32x4 __attribute__((ext_vector_type(4)));
typedef short  s16x8 __attribute__((ext_vector_type(8)));

__device__ __forceinline__ unsigned short f2bf(float f) {
    unsigned u = __float_as_uint(f);
    u = u + 0x7fffu + ((u >> 16) & 1u);   // RNE
    return (unsigned short)(u >> 16);
}
__device__ __forceinline__ float bf2f(unsigned short s) {
    return __uint_as_float(((unsigned)s) << 16);
}
__device__ __forceinline__ float sigm(float v) {
    return 1.0f / (1.0f + __expf(-v));
}
__device__ __forceinline__ void gll(const unsigned short* g, unsigned short* l) {
    __builtin_amdgcn_global_load_lds(
        (const __attribute__((address_space(1))) unsigned int*)g,
        (__attribute__((address_space(3))) unsigned int*)l, 16, 0, 0);
}

struct Params {
    const float *x, *c, *h;
    const float *Wxi, *Whi, *Bi, *Wxg, *Whg, *Bg;
    const float *Wxf, *Whf, *Bf, *Wxo, *Who, *Bo;
    const float *Why, *By;
    unsigned short *Xb, *Hb, *Wxb, *Whb, *Whyb, *Z, *HnB;
    float *ypart;
    float *y_out, *c_out, *h_out;
};

// ------------------------------------------------ phase 0: fp32->bf16 cast
__device__ __forceinline__ void cast_arr(const float* __restrict__ s,
                                         unsigned short* __restrict__ d,
                                         int n, int gtid) {
    for (int i = gtid * 4; i < n; i += NTHR * 4) {
        float4 v = *(const float4*)(s + i);
        ushort4 o;
        o.x = f2bf(v.x); o.y = f2bf(v.y); o.z = f2bf(v.z); o.w = f2bf(v.w);
        *(ushort4*)(d + i) = o;
    }
}

__device__ __forceinline__ void ph_cast(const Params& p, int gtid) {
    const int BE = B_SZ * E_SZ, BH = B_SZ * H_SZ;
    const int HE = H_SZ * E_SZ, HH_ = 1 << 22;   // H*H = 4M
    cast_arr(p.x,   p.Xb,                 BE,  gtid);
    cast_arr(p.h,   p.Hb,                 BH,  gtid);
    cast_arr(p.Wxi, p.Wxb,                HE,  gtid);
    cast_arr(p.Wxg, p.Wxb + (size_t)HE,   HE,  gtid);
    cast_arr(p.Wxf, p.Wxb + 2*(size_t)HE, HE,  gtid);
    cast_arr(p.Wxo, p.Wxb + 3*(size_t)HE, HE,  gtid);
    cast_arr(p.Whi, p.Whb,                HH_, gtid);
    cast_arr(p.Whg, p.Whb + (size_t)HH_,  HH_, gtid);
    cast_arr(p.Whf, p.Whb + 2*(size_t)HH_,HH_, gtid);
    cast_arr(p.Who, p.Whb + 3*(size_t)HH_,HH_, gtid);
    cast_arr(p.Why, p.Whyb,               HE,  gtid);
}

// --------------- dual-tile shared-A GEMM core (512 thr = 8 waves, BK=64)
// waves 0-3: acc += A[m0..][*] @ W0[nA..][*]^T ; waves 4-7: same with W1/nB.
// XOR-swizzled LDS (R5-verified, 0 bank conflicts). lA shared by all waves.
__device__ __forceinline__ void gemm_dual(
    const unsigned short* __restrict__ A,
    const unsigned short* __restrict__ W0,
    const unsigned short* __restrict__ W1,
    int ld, int kLen, int m0, int nA, int nB,
    unsigned short* lA, unsigned short* lB0, unsigned short* lB1,
    f32x4 acc[4][4], int t)
{
    const int lane = t & 63;
    const int w    = t >> 6;          // 0..7
    const int g    = w >> 2;          // tile group
    const int wg   = w & 3;
    const int wr   = (wg >> 1) << 6;
    const int wc   = (wg & 1) << 6;
    const int lr   = lane & 15;
    const int q4   = lane >> 4;

    const int srow = t >> 3;                       // 0..63
    const int scol = ((t & 7) ^ (srow & 7)) << 3;  // swizzled source col
    const unsigned short* gA  = A  + (size_t)(m0 + srow) * ld + scol;
    const unsigned short* gB0 = W0 + (size_t)(nA + srow) * ld + scol;
    const unsigned short* gB1 = W1 + (size_t)(nB + srow) * ld + scol;
    const size_t st64 = (size_t)64 * ld;
    unsigned short* myB = g ? lB1 : lB0;

    const int cb0 = ((q4    ) ^ (lr & 7)) << 3;
    const int cb1 = ((4 + q4) ^ (lr & 7)) << 3;

    for (int k0 = 0; k0 < kLen; k0 += 64) {
        gll(gA  + k0,        lA  + t * 8);
        gll(gA  + k0 + st64, lA  + (t + 512) * 8);
        gll(gB0 + k0,        lB0 + t * 8);
        gll(gB0 + k0 + st64, lB0 + (t + 512) * 8);
        gll(gB1 + k0,        lB1 + t * 8);
        gll(gB1 + k0 + st64, lB1 + (t + 512) * 8);
        __syncthreads();

#pragma unroll
        for (int ks = 0; ks < 2; ++ks) {
            const int cb = ks ? cb1 : cb0;
            s16x8 af[4], bfr[4];
#pragma unroll
            for (int i = 0; i < 4; ++i)
                af[i] = *(const s16x8*)(lA + (wr + i * 16 + lr) * 64 + cb);
#pragma unroll
            for (int j = 0; j < 4; ++j)
                bfr[j] = *(const s16x8*)(myB + (wc + j * 16 + lr) * 64 + cb);
#pragma unroll
            for (int i = 0; i < 4; ++i)
#pragma unroll
                for (int j = 0; j < 4; ++j)
                    acc[i][j] = __builtin_amdgcn_mfma_f32_16x16x32_bf16(
                        af[i], bfr[j], acc[i][j], 0, 0, 0);
        }
        __syncthreads();
    }
}

// ------------------------------------------------ phase 1: gate GEMMs
// 256 blocks: xcd(8) x j(4) x m(8); block does tiles nt0=xcd*8+j, nt1=nt0+4.
__device__ __forceinline__ void ph_gates(const Params& p, int b, int t,
                                         unsigned short* lA,
                                         unsigned short* lB0,
                                         unsigned short* lB1) {
    const size_t HE = (size_t)H_SZ * E_SZ, HH = (size_t)H_SZ * H_SZ;
    const size_t BH = (size_t)B_SZ * H_SZ;
    const int xcd = b & 7, i_ = b >> 3;
    const int j = i_ >> 3, mt = i_ & 7;
    const int nt0 = xcd * 8 + j, nt1 = nt0 + 4;
    const int q0 = nt0 >> 4, q1 = nt1 >> 4;
    const int n00 = (nt0 & 15) * 128, n01 = (nt1 & 15) * 128;
    const int m0 = mt * 128;

    f32x4 acc[4][4] = {};
    gemm_dual(p.Xb, p.Wxb + (size_t)q0 * HE, p.Wxb + (size_t)q1 * HE,
              E_SZ, E_SZ, m0, n00, n01, lA, lB0, lB1, acc, t);
    gemm_dual(p.Hb, p.Whb + (size_t)q0 * HH, p.Whb + (size_t)q1 * HH,
              H_SZ, H_SZ, m0, n00, n01, lA, lB0, lB1, acc, t);

    const int lane = t & 63, w = t >> 6;
    const int g = w >> 2, wg = w & 3;
    const int q = g ? q1 : q0;
    const int n0 = g ? n01 : n00;
    const float* bias = (q == 0) ? p.Bi : (q == 1) ? p.Bg : (q == 2) ? p.Bf : p.Bo;
    const int wr = (wg >> 1) << 6, wc = (wg & 1) << 6;
    const int lr = lane & 15, rq = (lane >> 4) << 2;
    unsigned short* Zq = p.Z + (size_t)q * BH;
#pragma unroll
    for (int i = 0; i < 4; ++i) {
#pragma unroll
        for (int jj = 0; jj < 4; ++jj) {
            const int n = n0 + wc + jj * 16 + lr;
            const float bv = bias[n];
#pragma unroll
            for (int r = 0; r < 4; ++r) {
                const int m = m0 + wr + i * 16 + rq + r;
                const float v = acc[i][jj][r] + bv;
                const float a = (q == 1) ? tanhf(v) : sigm(v);
                Zq[(size_t)m * H_SZ + n] = f2bf(a);
            }
        }
    }
}

// ------------------------------------------------ phase 2: cell update
__device__ __forceinline__ void ph_cell(const Params& p, int gtid) {
    const size_t BH = (size_t)B_SZ * H_SZ;
    for (int idx = gtid * 4; idx < (int)BH; idx += NTHR * 4) {
        ushort4 iu = *(const ushort4*)(p.Z + idx);
        ushort4 gu = *(const ushort4*)(p.Z + BH + idx);
        ushort4 fu = *(const ushort4*)(p.Z + 2 * BH + idx);
        ushort4 ou = *(const ushort4*)(p.Z + 3 * BH + idx);
        float4 cv = *(const float4*)(p.c + idx);

        float cn[4], hn[4];
        cn[0] = bf2f(fu.x) * cv.x + bf2f(iu.x) * bf2f(gu.x);
        cn[1] = bf2f(fu.y) * cv.y + bf2f(iu.y) * bf2f(gu.y);
        cn[2] = bf2f(fu.z) * cv.z + bf2f(iu.z) * bf2f(gu.z);
        cn[3] = bf2f(fu.w) * cv.w + bf2f(iu.w) * bf2f(gu.w);
        hn[0] = bf2f(ou.x) * cn[0];
        hn[1] = bf2f(ou.y) * cn[1];
        hn[2] = bf2f(ou.z) * cn[2];
        hn[3] = bf2f(ou.w) * cn[3];

        *(float4*)(p.c_out + idx) = make_float4(cn[0], cn[1], cn[2], cn[3]);
        *(float4*)(p.h_out + idx) = make_float4(hn[0], hn[1], hn[2], hn[3]);
        ushort4 hb;
        hb.x = f2bf(hn[0]); hb.y = f2bf(hn[1]);
        hb.z = f2bf(hn[2]); hb.w = f2bf(hn[3]);
        *(ushort4*)(p.HnB + idx) = hb;
    }
}

// ------------------------------------------------ phase 3: y GEMM, split-K 8
// 256 blocks: s(8) x npair(4) x m(8); K-chunk 256; dual n-tiles np, np+4.
__device__ __forceinline__ void ph_y(const Params& p, int b, int t,
                                     unsigned short* lA,
                                     unsigned short* lB0,
                                     unsigned short* lB1) {
    const size_t BE = (size_t)B_SZ * E_SZ;
    const int s = b >> 5, rem = b & 31;
    const int np = rem >> 3, mt = rem & 7;
    const int n00 = np * 128, n01 = (np + 4) * 128;
    const int m0 = mt * 128;

    const unsigned short* A = p.HnB  + s * 256;
    const unsigned short* W = p.Whyb + s * 256;

    f32x4 acc[4][4] = {};
    gemm_dual(A, W, W, H_SZ, 256, m0, n00, n01, lA, lB0, lB1, acc, t);

    const int lane = t & 63, w = t >> 6;
    const int g = w >> 2, wg = w & 3;
    const int n0 = g ? n01 : n00;
    const int wr = (wg >> 1) << 6, wc = (wg & 1) << 6;
    const int lr = lane & 15, rq = (lane >> 4) << 2;
    float* P = p.ypart + (size_t)s * BE;
#pragma unroll
    for (int i = 0; i < 4; ++i) {
#pragma unroll
        for (int jj = 0; jj < 4; ++jj) {
            const int n = n0 + wc + jj * 16 + lr;
#pragma unroll
            for (int r = 0; r < 4; ++r) {
                const int m = m0 + wr + i * 16 + rq + r;
                P[(size_t)m * E_SZ + n] = acc[i][jj][r];
            }
        }
    }
}

// ------------------------------------------------ phase 4: reduce + tanh
__device__ __forceinline__ void ph_reduce(const Params& p, int gtid) {
    const size_t BE = (size_t)B_SZ * E_SZ;
    for (int idx = gtid * 4; idx < (int)BE; idx += NTHR * 4) {
        float4 s0 = *(const float4*)(p.ypart + idx);
#pragma unroll
        for (int s = 1; s < 8; ++s) {
            float4 ps = *(const float4*)(p.ypart + (size_t)s * BE + idx);
            s0.x += ps.x; s0.y += ps.y; s0.z += ps.z; s0.w += ps.w;
        }
        const int col = idx & (E_SZ - 1);
        float4 bv = *(const float4*)(p.By + col);
        float4 o;
        o.x = tanhf(s0.x + bv.x);
        o.y = tanhf(s0.y + bv.y);
        o.z = tanhf(s0.z + bv.z);
        o.w = tanhf(s0.w + bv.w);
        *(float4*)(p.y_out + idx) = o;
    }
}

// =================== cooperative mega-kernel ==============================
__global__ __launch_bounds__(BLK, 2) void lstm_mega(Params p) {
    __shared__ unsigned short lA[128 * 64];
    __shared__ unsigned short lB0[128 * 64];
    __shared__ unsigned short lB1[128 * 64];
    cg::grid_group grid = cg::this_grid();
    const int t = threadIdx.x, b = blockIdx.x;
    const int gtid = b * BLK + t;

    ph_cast(p, gtid);
    __threadfence(); grid.sync();
    ph_gates(p, b, t, lA, lB0, lB1);
    __threadfence(); grid.sync();
    ph_cell(p, gtid);
    __threadfence(); grid.sync();
    ph_y(p, b, t, lA, lB0, lB1);
    __threadfence(); grid.sync();
    ph_reduce(p, gtid);
}

// =================== fallback: phases as ordinary kernels =================
__global__ __launch_bounds__(BLK) void k_cast(Params p) {
    ph_cast(p, blockIdx.x * BLK + threadIdx.x);
}
__global__ __launch_bounds__(BLK) void k_gates(Params p) {
    __shared__ unsigned short lA[128 * 64];
    __shared__ unsigned short lB0[128 * 64];
    __shared__ unsigned short lB1[128 * 64];
    ph_gates(p, blockIdx.x, threadIdx.x, lA, lB0, lB1);
}
__global__ __launch_bounds__(BLK) void k_cell(Params p) {
    ph_cell(p, blockIdx.x * BLK + threadIdx.x);
}
__global__ __launch_bounds__(BLK) void k_y(Params p) {
    __shared__ unsigned short lA[128 * 64];
    __shared__ unsigned short lB0[128 * 64];
    __shared__ unsigned short lB1[128 * 64];
    ph_y(p, blockIdx.x, threadIdx.x, lA, lB0, lB1);
}
__global__ __launch_bounds__(BLK) void k_reduce(Params p) {
    ph_reduce(p, blockIdx.x * BLK + threadIdx.x);
}

// ---------------------------------------------------------------- launch
extern "C" void kernel_launch(void* const* d_in, const int* in_sizes, int n_in,
                              void* d_out, int out_size, void* d_ws, size_t ws_size,
                              hipStream_t stream) {
    const size_t BE = (size_t)B_SZ * E_SZ, BH = (size_t)B_SZ * H_SZ;
    const size_t HE = (size_t)H_SZ * E_SZ, HH = (size_t)H_SZ * H_SZ;
    const size_t EH = (size_t)E_SZ * H_SZ;

    unsigned short* ws = (unsigned short*)d_ws;

    Params prm;
    prm.x   = (const float*)d_in[0];
    prm.c   = (const float*)d_in[1];
    prm.h   = (const float*)d_in[2];
    prm.Wxi = (const float*)d_in[3];
    prm.Whi = (const float*)d_in[4];
    prm.Bi  = (const float*)d_in[5];
    prm.Wxg = (const float*)d_in[6];
    prm.Whg = (const float*)d_in[7];
    prm.Bg  = (const float*)d_in[8];
    prm.Wxf = (const float*)d_in[9];
    prm.Whf = (const float*)d_in[10];
    prm.Bf  = (const float*)d_in[11];
    prm.Wxo = (const float*)d_in[12];
    prm.Who = (const float*)d_in[13];
    prm.Bo  = (const float*)d_in[14];
    prm.Why = (const float*)d_in[15];
    prm.By  = (const float*)d_in[16];

    prm.Xb   = ws;                    // BE bf16
    prm.Hb   = prm.Xb + BE;           // BH
    prm.Wxb  = prm.Hb + BH;           // 4*HE
    prm.Whb  = prm.Wxb + 4 * HE;      // 4*HH
    prm.Whyb = prm.Whb + 4 * HH;      // EH
    prm.Z    = prm.Whyb + EH;         // 4*BH bf16
    prm.HnB  = prm.Z + 4 * BH;        // BH
    // y partials (8*BE fp32 = 32 MB) overlay Wxb + first half of Whb
    // (both dead after phase 1; Whyb at +48 MB is NOT overlapped)
    prm.ypart = (float*)prm.Wxb;

    float* y_out = (float*)d_out;
    prm.y_out = y_out;
    prm.c_out = y_out + BE;
    prm.h_out = prm.c_out + BH;

    // capture-safe support queries, then coop launch with checked fallback
    int dev = 0;
    hipGetDevice(&dev);
    int coop_ok = 0;
    hipDeviceGetAttribute(&coop_ok, hipDeviceAttributeCooperativeLaunch, dev);
    int maxb = 0;
    hipOccupancyMaxActiveBlocksPerMultiprocessor(&maxb, lstm_mega, BLK, 0);

    bool done = false;
    if (coop_ok && maxb >= 1) {
        void* args[] = { (void*)&prm };
        hipError_t e = hipLaunchCooperativeKernel((const void*)lstm_mega,
                                                  dim3(GRID), dim3(BLK),
                                                  args, 0, stream);
        done = (e == hipSuccess);
    }
    if (!done) {
        hipLaunchKernelGGL(k_cast,   dim3(GRID), dim3(BLK), 0, stream, prm);
        hipLaunchKernelGGL(k_gates,  dim3(GRID), dim3(BLK), 0, stream, prm);
        hipLaunchKernelGGL(k_cell,   dim3(GRID), dim3(BLK), 0, stream, prm);
        hipLaunchKernelGGL(k_y,      dim3(GRID), dim3(BLK), 0, stream, prm);
        hipLaunchKernelGGL(k_reduce, dim3(GRID), dim3(BLK), 0, stream, prm);
    }
}